// Round 4
// baseline (1209.024 us; speedup 1.0000x reference)
//
#include <hip/hip_runtime.h>
#include <hip/hip_bf16.h>

using bf16_t = __hip_bfloat16;
using bf16x8 = __attribute__((ext_vector_type(8))) __bf16;
using f32x4  = __attribute__((ext_vector_type(4))) float;

#define MFMA(a, b, c) __builtin_amdgcn_mfma_f32_16x16x32_bf16((a), (b), (c), 0, 0, 0)

// B=8, C=256, N=4096(=64x64), 16 groups of 16 channels. f32 I/O, bf16 internal.
// Workspace (bf16 elems):
//   [0)           4x65536   converted weights q,k,v,proj
//   [262144)      hn_t, yn_t, q_t, k_t, v   : 5 x (B,N,C)/(B,C,N) = 5 x 8M elems
//   h_t aliases yn_t.

// -------- convert 4 weight matrices (256x256 f32) to bf16 ----------------
__global__ __launch_bounds__(256) void cvtw_kernel(
    const float* __restrict__ w0, const float* __restrict__ w1,
    const float* __restrict__ w2, const float* __restrict__ w3,
    bf16_t* __restrict__ dst)
{
  const float* s;
  switch (blockIdx.y) {
    case 0: s = w0; break;
    case 1: s = w1; break;
    case 2: s = w2; break;
    default: s = w3; break;
  }
  bf16_t* d = dst + (long)blockIdx.y * 65536;
  const int i = (blockIdx.x * 256 + threadIdx.x) * 4;   // 64 blocks x 256 thr x 4
  float4 v = *(const float4*)(s + i);
  d[i + 0] = __float2bfloat16(v.x);
  d[i + 1] = __float2bfloat16(v.y);
  d[i + 2] = __float2bfloat16(v.z);
  d[i + 3] = __float2bfloat16(v.w);
}

// ---------------- GroupNorm (f32 in) -> transposed (N, C) bf16 -----------
__global__ __launch_bounds__(256) void gnorm_kernel(
    const float* __restrict__ xy,
    const float* __restrict__ nw,
    const float* __restrict__ nb,
    bf16_t* __restrict__ hn_t,
    bf16_t* __restrict__ yn_t)
{
  const int bx    = blockIdx.x;      // 256 blocks = 8 b * 2 which * 16 g
  const int b     = bx >> 5;
  const int rest  = bx & 31;
  const int which = rest >> 4;       // 0: x -> hn_t, 1: y -> yn_t
  const int g     = rest & 15;

  const float* src = xy + (((long)b * 512 + which * 256 + g * 16) << 12);
  bf16_t* dst = (which ? yn_t : hn_t) + ((long)b << 20) + g * 16;

  const int tid = threadIdx.x;

  // pass 1: mean / var over 16 ch * 4096 px = 65536 f32 (float4, coalesced)
  float sum = 0.f, ss = 0.f;
  const float4* src4 = (const float4*)src;
  for (int i = tid; i < 16384; i += 256) {
    float4 v = src4[i];
    sum += (v.x + v.y) + (v.z + v.w);
    ss = fmaf(v.x, v.x, ss); ss = fmaf(v.y, v.y, ss);
    ss = fmaf(v.z, v.z, ss); ss = fmaf(v.w, v.w, ss);
  }
  #pragma unroll
  for (int off = 32; off > 0; off >>= 1) {
    sum += __shfl_down(sum, off);
    ss  += __shfl_down(ss, off);
  }
  __shared__ float rbuf[8];
  const int w = tid >> 6, lane = tid & 63;
  if (lane == 0) { rbuf[w] = sum; rbuf[4 + w] = ss; }
  __syncthreads();
  const float inv = 1.f / 65536.f;
  const float mu  = (rbuf[0] + rbuf[1] + rbuf[2] + rbuf[3]) * inv;
  const float var = (rbuf[4] + rbuf[5] + rbuf[6] + rbuf[7]) * inv - mu * mu;
  const float rs  = rsqrtf(var + 1e-6f);

  // pass 2: normalize + transpose-write. 16 consecutive lanes -> 32B chunks.
  const int   cl = tid & 15;
  const float a  = nw[g * 16 + cl] * rs;
  const float c  = nb[g * 16 + cl] - mu * a;
  const float* srow = src + ((long)cl << 12);
  for (int n = tid >> 4; n < 4096; n += 16) {
    dst[((long)n << 8) + cl] = __float2bfloat16(fmaf(srow[n], a, c));
  }
}

// ---------------- NT GEMM: C[m][n] = sum_k A[m][k] * B[n][k]  (K = 256) ---
// block: 256 thr = 4 waves; tile 64(M) x 64(N); wave w owns rows [m0+16w, +16)
template <bool F32OUT>
__global__ __launch_bounds__(256) void gemm_nt_kernel(
    const bf16_t* __restrict__ A,  long sA,
    const bf16_t* __restrict__ Bm, long sB,
    void* __restrict__ Co_,        long sC,
    int Nn,
    const float* __restrict__ bias, int bias_row,
    const float* __restrict__ resid, long sR)
{
  const int b = blockIdx.z;
  A  += (long)b * sA;
  Bm += (long)b * sB;

  const int tid  = threadIdx.x;
  const int w    = tid >> 6, lane = tid & 63;
  const int rowq = lane & 15, kg = lane >> 4;     // frag row / k-group
  const int m0   = blockIdx.x * 64 + w * 16;
  const int n0   = blockIdx.y * 64;

  f32x4 acc[4] = {};
  const bf16x8* arow = (const bf16x8*)(A + (long)(m0 + rowq) * 256 + kg * 8);
  #pragma unroll
  for (int kc = 0; kc < 8; ++kc) {
    bf16x8 af = arow[kc * 4];
    #pragma unroll
    for (int nt = 0; nt < 4; ++nt) {
      bf16x8 bfr = *(const bf16x8*)(Bm + (long)(n0 + nt * 16 + rowq) * 256 + kc * 32 + kg * 8);
      acc[nt] = MFMA(af, bfr, acc[nt]);
    }
  }
  // C/D layout: col = lane&15, row = (lane>>4)*4 + r
  const int r0 = kg * 4;
  #pragma unroll
  for (int nt = 0; nt < 4; ++nt) {
    #pragma unroll
    for (int r = 0; r < 4; ++r) {
      const int row = m0 + r0 + r;
      const int col = n0 + nt * 16 + rowq;
      float vv = acc[nt][r] + bias[bias_row ? row : col];
      if (resid) vv += resid[(long)b * sR + (long)row * Nn + col];
      const long ci = (long)b * sC + (long)row * Nn + col;
      if (F32OUT) ((float*)Co_)[ci] = vv;
      else        ((bf16_t*)Co_)[ci] = __float2bfloat16(vv);
    }
  }
}

// ---------------- Flash attention: O = softmax(Q K^T / 16) V ---------------
// grid (64 q-tiles, 8 batches); block = 4 waves, wave owns 16 q rows.
__global__ __launch_bounds__(256) void attn_kernel(
    const bf16_t* __restrict__ Q,   // (B, N, C)
    const bf16_t* __restrict__ Kt,  // (B, N, C)
    const bf16_t* __restrict__ V,   // (B, C, N)
    bf16_t* __restrict__ Ht)        // (B, N, C)
{
  const int b  = blockIdx.y;
  const long bo = (long)b << 20;    // b * 4096 * 256
  const bf16_t* q_t = Q  + bo;
  const bf16_t* k_t = Kt + bo;
  const bf16_t* vb  = V  + bo;
  bf16_t*       h_t = Ht + bo;

  const int tid  = threadIdx.x;
  const int w    = tid >> 6, lane = tid & 63;
  const int rowq = lane & 15, kg = lane >> 4;
  const int q0   = blockIdx.x * 64 + w * 16;

  __shared__ bf16_t p_lds[4][16][72];   // stride 72 elems (144B, 16B-aligned)

  // Q fragments in registers: 16 rows x 256 dims
  bf16x8 qf[8];
  {
    const bf16x8* qrow = (const bf16x8*)(q_t + (long)(q0 + rowq) * 256 + kg * 8);
    #pragma unroll
    for (int kc = 0; kc < 8; ++kc) qf[kc] = qrow[kc * 4];
  }

  f32x4 o[16] = {};
  float m[4] = { -1e30f, -1e30f, -1e30f, -1e30f };
  float l[4] = { 0.f, 0.f, 0.f, 0.f };

  for (int kv0 = 0; kv0 < 4096; kv0 += 64) {
    // S = Q K^T for 16 q-rows x 64 kv
    f32x4 s[4] = {};
    #pragma unroll
    for (int nt = 0; nt < 4; ++nt) {
      const bf16x8* krow = (const bf16x8*)(k_t + (long)(kv0 + nt * 16 + rowq) * 256 + kg * 8);
      #pragma unroll
      for (int kc = 0; kc < 8; ++kc) s[nt] = MFMA(qf[kc], krow[kc * 4], s[nt]);
    }
    // online softmax; lane holds rows kg*4+r, col nt*16+rowq
    float sv[4][4], p[4][4], rmax[4], rsum[4], mn[4], al[4];
    #pragma unroll
    for (int nt = 0; nt < 4; ++nt)
      #pragma unroll
      for (int r = 0; r < 4; ++r) sv[nt][r] = s[nt][r] * 0.0625f;
    #pragma unroll
    for (int r = 0; r < 4; ++r)
      rmax[r] = fmaxf(fmaxf(sv[0][r], sv[1][r]), fmaxf(sv[2][r], sv[3][r]));
    #pragma unroll
    for (int off = 1; off < 16; off <<= 1)
      #pragma unroll
      for (int r = 0; r < 4; ++r) rmax[r] = fmaxf(rmax[r], __shfl_xor(rmax[r], off));
    #pragma unroll
    for (int r = 0; r < 4; ++r) {
      mn[r] = fmaxf(m[r], rmax[r]);
      al[r] = __expf(m[r] - mn[r]);
      m[r]  = mn[r];
    }
    #pragma unroll
    for (int nt = 0; nt < 4; ++nt)
      #pragma unroll
      for (int r = 0; r < 4; ++r) p[nt][r] = __expf(sv[nt][r] - mn[r]);
    #pragma unroll
    for (int r = 0; r < 4; ++r) rsum[r] = (p[0][r] + p[1][r]) + (p[2][r] + p[3][r]);
    #pragma unroll
    for (int off = 1; off < 16; off <<= 1)
      #pragma unroll
      for (int r = 0; r < 4; ++r) rsum[r] += __shfl_xor(rsum[r], off);
    #pragma unroll
    for (int r = 0; r < 4; ++r) l[r] = l[r] * al[r] + rsum[r];
    #pragma unroll
    for (int ct = 0; ct < 16; ++ct)
      #pragma unroll
      for (int r = 0; r < 4; ++r) o[ct][r] *= al[r];

    // P (C-layout) -> LDS -> A-fragment layout
    __syncthreads();   // previous iter's P reads done before overwrite
    #pragma unroll
    for (int nt = 0; nt < 4; ++nt)
      #pragma unroll
      for (int r = 0; r < 4; ++r)
        p_lds[w][kg * 4 + r][nt * 16 + rowq] = __float2bfloat16(p[nt][r]);
    __syncthreads();   // writes visible

    // O += P V   (V (C,N): B-frag = 8 contiguous kv at row c)
    #pragma unroll
    for (int kh = 0; kh < 2; ++kh) {
      bf16x8 pf = *(const bf16x8*)(&p_lds[w][rowq][kh * 32 + kg * 8]);
      #pragma unroll
      for (int ct = 0; ct < 16; ++ct) {
        bf16x8 vf = *(const bf16x8*)(vb + ((long)(ct * 16 + rowq) << 12) + kv0 + kh * 32 + kg * 8);
        o[ct] = MFMA(pf, vf, o[ct]);
      }
    }
  }

  float il[4];
  #pragma unroll
  for (int r = 0; r < 4; ++r) il[r] = 1.f / l[r];
  #pragma unroll
  for (int ct = 0; ct < 16; ++ct)
    #pragma unroll
    for (int r = 0; r < 4; ++r)
      h_t[(long)(q0 + kg * 4 + r) * 256 + ct * 16 + rowq] = __float2bfloat16(o[ct][r] * il[r]);
}

extern "C" void kernel_launch(void* const* d_in, const int* in_sizes, int n_in,
                              void* d_out, int out_size, void* d_ws, size_t ws_size,
                              hipStream_t stream)
{
  const float* xy  = (const float*)d_in[0];
  const float* nw  = (const float*)d_in[1];
  const float* nb  = (const float*)d_in[2];
  const float* q_w = (const float*)d_in[3];
  const float* q_b = (const float*)d_in[4];
  const float* k_w = (const float*)d_in[5];
  const float* k_b = (const float*)d_in[6];
  const float* v_w = (const float*)d_in[7];
  const float* v_b = (const float*)d_in[8];
  const float* p_w = (const float*)d_in[9];
  const float* p_b = (const float*)d_in[10];
  float*  out = (float*)d_out;
  bf16_t* ws  = (bf16_t*)d_ws;

  const long SZ = (long)8 * 4096 * 256;   // elems per (B,N,C) buffer
  bf16_t* wq   = ws;                      // 4 x 65536 bf16 weights
  bf16_t* wk   = ws + 65536;
  bf16_t* wv   = ws + 131072;
  bf16_t* wp   = ws + 196608;
  bf16_t* hn_t = ws + 262144;
  bf16_t* yn_t = hn_t + SZ;
  bf16_t* q_t  = hn_t + 2 * SZ;
  bf16_t* k_t  = hn_t + 3 * SZ;
  bf16_t* vbuf = hn_t + 4 * SZ;
  bf16_t* h_t  = yn_t;                    // yn dead after q GEMM

  const long nc = (long)4096 * 256;

  cvtw_kernel<<<dim3(64, 4), 256, 0, stream>>>(q_w, k_w, v_w, p_w, wq);

  gnorm_kernel<<<256, 256, 0, stream>>>(xy, nw, nb, hn_t, yn_t);

  // q_t(N,256) = yn_t x q_w^T + q_b[col]
  gemm_nt_kernel<false><<<dim3(64, 4, 8), 256, 0, stream>>>(
      yn_t, nc, wq, 0, q_t, nc, 256, q_b, 0, nullptr, 0);
  // k_t(N,256) = hn_t x k_w^T + k_b[col]
  gemm_nt_kernel<false><<<dim3(64, 4, 8), 256, 0, stream>>>(
      hn_t, nc, wk, 0, k_t, nc, 256, k_b, 0, nullptr, 0);
  // v(256,N) = v_w x hn_t^T + v_b[row]
  gemm_nt_kernel<false><<<dim3(4, 64, 8), 256, 0, stream>>>(
      wv, 0, hn_t, nc, vbuf, nc, 4096, v_b, 1, nullptr, 0);

  attn_kernel<<<dim3(64, 8), 256, 0, stream>>>(q_t, k_t, vbuf, h_t);

  // out(256,N) = proj_w x h_t^T + proj_b[row] + x   (f32 out, residual from xy)
  gemm_nt_kernel<true><<<dim3(4, 64, 8), 256, 0, stream>>>(
      wp, 0, h_t, nc, out, nc, 4096, p_b, 1, xy, (long)512 * 4096);
}

// Round 5
// 475.981 us; speedup vs baseline: 2.5401x; 2.5401x over previous
//
#include <hip/hip_runtime.h>
#include <hip/hip_bf16.h>

using bf16_t = __hip_bfloat16;
using bf16x8 = __attribute__((ext_vector_type(8))) __bf16;
using f32x4  = __attribute__((ext_vector_type(4))) float;

#define MFMA(a, b, c) __builtin_amdgcn_mfma_f32_16x16x32_bf16((a), (b), (c), 0, 0, 0)

#define GLOAD_LDS(g, l) __builtin_amdgcn_global_load_lds(                      \
    (const __attribute__((address_space(1))) void*)(g),                        \
    (__attribute__((address_space(3))) void*)(l), 16, 0, 0)

// B=8, C=256, N=4096(=64x64), 16 groups of 16 channels. f32 I/O, bf16 internal.

// -------- convert 4 weight matrices (256x256 f32) to bf16 ----------------
__global__ __launch_bounds__(256) void cvtw_kernel(
    const float* __restrict__ w0, const float* __restrict__ w1,
    const float* __restrict__ w2, const float* __restrict__ w3,
    bf16_t* __restrict__ dst)
{
  const float* s;
  switch (blockIdx.y) {
    case 0: s = w0; break;
    case 1: s = w1; break;
    case 2: s = w2; break;
    default: s = w3; break;
  }
  bf16_t* d = dst + (long)blockIdx.y * 65536;
  const int i = (blockIdx.x * 256 + threadIdx.x) * 4;
  float4 v = *(const float4*)(s + i);
  d[i + 0] = __float2bfloat16(v.x);
  d[i + 1] = __float2bfloat16(v.y);
  d[i + 2] = __float2bfloat16(v.z);
  d[i + 3] = __float2bfloat16(v.w);
}

// ---------------- GroupNorm (f32 in) -> transposed (N, C) bf16 -----------
__global__ __launch_bounds__(256) void gnorm_kernel(
    const float* __restrict__ xy,
    const float* __restrict__ nw,
    const float* __restrict__ nb,
    bf16_t* __restrict__ hn_t,
    bf16_t* __restrict__ yn_t)
{
  const int bx    = blockIdx.x;      // 256 blocks = 8 b * 2 which * 16 g
  const int b     = bx >> 5;
  const int rest  = bx & 31;
  const int which = rest >> 4;
  const int g     = rest & 15;

  const float* src = xy + (((long)b * 512 + which * 256 + g * 16) << 12);
  bf16_t* dst = (which ? yn_t : hn_t) + ((long)b << 20) + g * 16;

  const int tid = threadIdx.x;

  float sum = 0.f, ss = 0.f;
  const float4* src4 = (const float4*)src;
  for (int i = tid; i < 16384; i += 256) {
    float4 v = src4[i];
    sum += (v.x + v.y) + (v.z + v.w);
    ss = fmaf(v.x, v.x, ss); ss = fmaf(v.y, v.y, ss);
    ss = fmaf(v.z, v.z, ss); ss = fmaf(v.w, v.w, ss);
  }
  #pragma unroll
  for (int off = 32; off > 0; off >>= 1) {
    sum += __shfl_down(sum, off);
    ss  += __shfl_down(ss, off);
  }
  __shared__ float rbuf[8];
  const int w = tid >> 6, lane = tid & 63;
  if (lane == 0) { rbuf[w] = sum; rbuf[4 + w] = ss; }
  __syncthreads();
  const float inv = 1.f / 65536.f;
  const float mu  = (rbuf[0] + rbuf[1] + rbuf[2] + rbuf[3]) * inv;
  const float var = (rbuf[4] + rbuf[5] + rbuf[6] + rbuf[7]) * inv - mu * mu;
  const float rs  = rsqrtf(var + 1e-6f);

  const int   cl = tid & 15;
  const float a  = nw[g * 16 + cl] * rs;
  const float c  = nb[g * 16 + cl] - mu * a;
  const float* srow = src + ((long)cl << 12);
  for (int n = tid >> 4; n < 4096; n += 16) {
    dst[((long)n << 8) + cl] = __float2bfloat16(fmaf(srow[n], a, c));
  }
}

// ---------------- NT GEMM: C[m][n] = sum_k A[m][k] * B[n][k]  (K = 256) ---
template <bool F32OUT>
__global__ __launch_bounds__(256) void gemm_nt_kernel(
    const bf16_t* __restrict__ A,  long sA,
    const bf16_t* __restrict__ Bm, long sB,
    void* __restrict__ Co_,        long sC,
    int Nn,
    const float* __restrict__ bias, int bias_row,
    const float* __restrict__ resid, long sR)
{
  const int b = blockIdx.z;
  A  += (long)b * sA;
  Bm += (long)b * sB;

  const int tid  = threadIdx.x;
  const int w    = tid >> 6, lane = tid & 63;
  const int rowq = lane & 15, kg = lane >> 4;
  const int m0   = blockIdx.x * 64 + w * 16;
  const int n0   = blockIdx.y * 64;

  f32x4 acc[4] = {};
  const bf16x8* arow = (const bf16x8*)(A + (long)(m0 + rowq) * 256 + kg * 8);
  #pragma unroll
  for (int kc = 0; kc < 8; ++kc) {
    bf16x8 af = arow[kc * 4];
    #pragma unroll
    for (int nt = 0; nt < 4; ++nt) {
      bf16x8 bfr = *(const bf16x8*)(Bm + (long)(n0 + nt * 16 + rowq) * 256 + kc * 32 + kg * 8);
      acc[nt] = MFMA(af, bfr, acc[nt]);
    }
  }
  const int r0 = kg * 4;
  #pragma unroll
  for (int nt = 0; nt < 4; ++nt) {
    #pragma unroll
    for (int r = 0; r < 4; ++r) {
      const int row = m0 + r0 + r;
      const int col = n0 + nt * 16 + rowq;
      float vv = acc[nt][r] + bias[bias_row ? row : col];
      if (resid) vv += resid[(long)b * sR + (long)row * Nn + col];
      const long ci = (long)b * sC + (long)row * Nn + col;
      if (F32OUT) ((float*)Co_)[ci] = vv;
      else        ((bf16_t*)Co_)[ci] = __float2bfloat16(vv);
    }
  }
}

// ---------------- Flash attention: O = softmax(Q K^T / 16) V ---------------
// grid (32 q-tiles, 8 batches); block = 8 waves x 16 q-rows = 128 q-rows.
// K/V tiles (KVBLK=64) double-buffered in LDS via global_load_lds;
// both-sides XOR swizzle (16B chunk ^= row&7) for conflict-free ds_read_b128.
__global__ __launch_bounds__(512, 2) void attn_kernel(
    const bf16_t* __restrict__ Q,   // (B, N, C)
    const bf16_t* __restrict__ Kt,  // (B, N, C)
    const bf16_t* __restrict__ V,   // (B, C, N)
    bf16_t* __restrict__ Ht)        // (B, N, C)
{
  __shared__ bf16_t k_lds[2][64 * 256];   // 32KB/buf; row = kv (512B, 32 chunks)
  __shared__ bf16_t v_lds[2][256 * 64];   // 32KB/buf; row = c  (128B, 8 chunks)
  __shared__ bf16_t p_lds[8][16][72];     // per-wave P tile, stride-72 (bank-spread)

  const int b  = blockIdx.y;
  const long bo = (long)b << 20;
  const bf16_t* q_t = Q  + bo;
  const bf16_t* k_t = Kt + bo;
  const bf16_t* vb  = V  + bo;
  bf16_t*       h_t = Ht + bo;

  const int tid  = threadIdx.x;
  const int w    = tid >> 6, lane = tid & 63;
  const int rowq = lane & 15, kg = lane >> 4;
  const int q0   = blockIdx.x * 128 + w * 16;

  // staging sources (swizzle-inverse pre-applied): LDS slot (row, chunk j)
  // holds global chunk (row, j ^ (row&7)).
  const bf16_t* ksrc[4];
  const bf16_t* vsrc[4];
  int koff[4], voff[4];
  #pragma unroll
  for (int it = 0; it < 4; ++it) {
    const int cl = it * 512 + tid;          // chunk-linear 0..2047
    const int r  = cl >> 5, j = cl & 31;    // K: 64 rows x 32 chunks
    ksrc[it] = k_t + r * 256 + ((j ^ (r & 7)) << 3);
    koff[it] = cl << 3;
    const int c = cl >> 3, jv = cl & 7;     // V: 256 rows x 8 chunks
    vsrc[it] = vb + (long)c * 4096 + ((jv ^ (c & 7)) << 3);
    voff[it] = cl << 3;
  }

  // Q fragments in registers: 16 rows x 256 dims
  bf16x8 qf[8];
  {
    const bf16x8* qrow = (const bf16x8*)(q_t + (long)(q0 + rowq) * 256 + kg * 8);
    #pragma unroll
    for (int kc = 0; kc < 8; ++kc) qf[kc] = qrow[kc * 4];
  }

  f32x4 o[16] = {};
  float m[4] = { -1e30f, -1e30f, -1e30f, -1e30f };
  float l[4] = { 0.f, 0.f, 0.f, 0.f };

  // prologue: stage tile 0 into buf 0
  #pragma unroll
  for (int it = 0; it < 4; ++it) GLOAD_LDS(ksrc[it], &k_lds[0][koff[it]]);
  #pragma unroll
  for (int it = 0; it < 4; ++it) GLOAD_LDS(vsrc[it], &v_lds[0][voff[it]]);

  int cur = 0;
  for (int t = 0; t < 64; ++t) {
    // drain own loads (vmcnt 0) + barrier: buf[cur] fully staged by all waves;
    // also: every wave finished reading buf[cur^1] last iter -> safe to restage.
    __syncthreads();
    if (t < 63) {
      const int kvn = (t + 1) << 6;
      #pragma unroll
      for (int it = 0; it < 4; ++it)
        GLOAD_LDS(ksrc[it] + (long)kvn * 256, &k_lds[cur ^ 1][koff[it]]);
      #pragma unroll
      for (int it = 0; it < 4; ++it)
        GLOAD_LDS(vsrc[it] + kvn, &v_lds[cur ^ 1][voff[it]]);
    }

    // S = Q K^T for 16 q-rows x 64 kv, K from LDS (swizzled read)
    f32x4 s[4] = {};
    #pragma unroll
    for (int nt = 0; nt < 4; ++nt) {
      const int r = nt * 16 + rowq;
      #pragma unroll
      for (int kc = 0; kc < 8; ++kc) {
        const int jl = kc * 4 + kg;
        bf16x8 kf = *(const bf16x8*)(&k_lds[cur][r * 256 + ((jl ^ (r & 7)) << 3)]);
        s[nt] = MFMA(qf[kc], kf, s[nt]);
      }
    }

    // online softmax; lane holds rows kg*4+r, col nt*16+rowq
    float sv[4][4], p[4][4], rmax[4], rsum[4], mn[4], al[4];
    #pragma unroll
    for (int nt = 0; nt < 4; ++nt)
      #pragma unroll
      for (int r = 0; r < 4; ++r) sv[nt][r] = s[nt][r] * 0.0625f;
    #pragma unroll
    for (int r = 0; r < 4; ++r)
      rmax[r] = fmaxf(fmaxf(sv[0][r], sv[1][r]), fmaxf(sv[2][r], sv[3][r]));
    #pragma unroll
    for (int off = 1; off < 16; off <<= 1)
      #pragma unroll
      for (int r = 0; r < 4; ++r) rmax[r] = fmaxf(rmax[r], __shfl_xor(rmax[r], off));
    #pragma unroll
    for (int r = 0; r < 4; ++r) {
      mn[r] = fmaxf(m[r], rmax[r]);
      al[r] = __expf(m[r] - mn[r]);
      m[r]  = mn[r];
    }
    #pragma unroll
    for (int nt = 0; nt < 4; ++nt)
      #pragma unroll
      for (int r = 0; r < 4; ++r) p[nt][r] = __expf(sv[nt][r] - mn[r]);
    #pragma unroll
    for (int r = 0; r < 4; ++r) rsum[r] = (p[0][r] + p[1][r]) + (p[2][r] + p[3][r]);
    #pragma unroll
    for (int off = 1; off < 16; off <<= 1)
      #pragma unroll
      for (int r = 0; r < 4; ++r) rsum[r] += __shfl_xor(rsum[r], off);
    #pragma unroll
    for (int r = 0; r < 4; ++r) l[r] = l[r] * al[r] + rsum[r];
    #pragma unroll
    for (int ct = 0; ct < 16; ++ct)
      #pragma unroll
      for (int r = 0; r < 4; ++r) o[ct][r] *= al[r];

    // P (C-layout) -> per-wave LDS slice -> A-fragment layout (intra-wave only)
    #pragma unroll
    for (int nt = 0; nt < 4; ++nt)
      #pragma unroll
      for (int r = 0; r < 4; ++r)
        p_lds[w][kg * 4 + r][nt * 16 + rowq] = __float2bfloat16(p[nt][r]);
    asm volatile("s_waitcnt lgkmcnt(0)" ::: "memory");
    __builtin_amdgcn_sched_barrier(0);

    // O += P V, V from LDS (swizzled read)
    #pragma unroll
    for (int kh = 0; kh < 2; ++kh) {
      bf16x8 pf = *(const bf16x8*)(&p_lds[w][rowq][kh * 32 + kg * 8]);
      #pragma unroll
      for (int ct = 0; ct < 16; ++ct) {
        const int c  = ct * 16 + rowq;
        const int jl = kh * 4 + kg;
        bf16x8 vf = *(const bf16x8*)(&v_lds[cur][c * 64 + ((jl ^ (c & 7)) << 3)]);
        o[ct] = MFMA(pf, vf, o[ct]);
      }
    }
    cur ^= 1;
  }

  float il[4];
  #pragma unroll
  for (int r = 0; r < 4; ++r) il[r] = 1.f / l[r];
  #pragma unroll
  for (int ct = 0; ct < 16; ++ct)
    #pragma unroll
    for (int r = 0; r < 4; ++r)
      h_t[(long)(q0 + kg * 4 + r) * 256 + ct * 16 + rowq] = __float2bfloat16(o[ct][r] * il[r]);
}

extern "C" void kernel_launch(void* const* d_in, const int* in_sizes, int n_in,
                              void* d_out, int out_size, void* d_ws, size_t ws_size,
                              hipStream_t stream)
{
  const float* xy  = (const float*)d_in[0];
  const float* nw  = (const float*)d_in[1];
  const float* nb  = (const float*)d_in[2];
  const float* q_w = (const float*)d_in[3];
  const float* q_b = (const float*)d_in[4];
  const float* k_w = (const float*)d_in[5];
  const float* k_b = (const float*)d_in[6];
  const float* v_w = (const float*)d_in[7];
  const float* v_b = (const float*)d_in[8];
  const float* p_w = (const float*)d_in[9];
  const float* p_b = (const float*)d_in[10];
  float*  out = (float*)d_out;
  bf16_t* ws  = (bf16_t*)d_ws;

  const long SZ = (long)8 * 4096 * 256;
  bf16_t* wq   = ws;
  bf16_t* wk   = ws + 65536;
  bf16_t* wv   = ws + 131072;
  bf16_t* wp   = ws + 196608;
  bf16_t* hn_t = ws + 262144;
  bf16_t* yn_t = hn_t + SZ;
  bf16_t* q_t  = hn_t + 2 * SZ;
  bf16_t* k_t  = hn_t + 3 * SZ;
  bf16_t* vbuf = hn_t + 4 * SZ;
  bf16_t* h_t  = yn_t;                    // yn dead after q GEMM

  const long nc = (long)4096 * 256;

  cvtw_kernel<<<dim3(64, 4), 256, 0, stream>>>(q_w, k_w, v_w, p_w, wq);

  gnorm_kernel<<<256, 256, 0, stream>>>(xy, nw, nb, hn_t, yn_t);

  gemm_nt_kernel<false><<<dim3(64, 4, 8), 256, 0, stream>>>(
      yn_t, nc, wq, 0, q_t, nc, 256, q_b, 0, nullptr, 0);
  gemm_nt_kernel<false><<<dim3(64, 4, 8), 256, 0, stream>>>(
      hn_t, nc, wk, 0, k_t, nc, 256, k_b, 0, nullptr, 0);
  gemm_nt_kernel<false><<<dim3(4, 64, 8), 256, 0, stream>>>(
      wv, 0, hn_t, nc, vbuf, nc, 4096, v_b, 1, nullptr, 0);

  attn_kernel<<<dim3(32, 8), 512, 0, stream>>>(q_t, k_t, vbuf, h_t);

  gemm_nt_kernel<true><<<dim3(4, 64, 8), 256, 0, stream>>>(
      wp, 0, h_t, nc, out, nc, 4096, p_b, 1, xy, (long)512 * 4096);
}